// Round 13
// baseline (3555.182 us; speedup 1.0000x reference)
//
#include <hip/hip_runtime.h>
#include <hip/hip_bf16.h>

#define GN 16384
#define GH 16
#define GK 16
#define GL 4
#define HPS 20            // padded h row: 16 features + sq + 3 pad (80 B)

#define TPB 256           // knn block: 4 waves x 4 rows each = 16 rows
#define RPB 16            // rows per knn block
#define CAP 96            // collect buffer capacity per row (E[cnt]=64)
#define BSTR 97           // buffer row stride
#define MSTR 132          // phase-1 merge row stride (128 vals + pad)
// LDS floats: 2 tile-bufs (1024 f4 + 256 sq each) + bufd/bufj/cnt/tau
#define TREG  (2*4096 + 2*256)                 // 8704
#define LDS_TOT (TREG + 2*RPB*BSTR + 2*RPB)    // 11840 floats = 47.4 KB

#define INFF __builtin_inff()

// workspace float-offsets
#define OFF_H     0
#define OFF_IDX   (5*GN*HPS)
#define OFF_FLAGS (OFF_IDX + GN*GK)
#define OFF_XF    (OFF_FLAGS + GN)
#define OFF_EMBW  (OFF_XF + GN*3)
#define OFF_EMBB  (OFF_EMBW + 3*GH)
#define OFF_W1    (OFF_EMBB + GH)
#define OFF_B1    (OFF_W1 + GL*2*GH*GH)
#define OFF_W2    (OFF_B1 + GL*GH)
#define OFF_B2    (OFF_W2 + GL*GH*GH)
#define OFF_OW    (OFF_B2 + GL*GH)
#define OFF_OB    (OFF_OW + GL*GH*3)
#define OFF_DFLAG (OFF_OB + 4)
#define OFF_HT    (OFF_DFLAG + 8)     // 4 float4-planes (GN*16 f) + sq plane (GN f)
#define OFF_HTS   (OFF_HT + GN*16)

// ---------------------------------------------------------------------------
__device__ __forceinline__ float rfl(float x)
{
    return __uint_as_float(__builtin_amdgcn_readfirstlane(__float_as_uint(x)));
}

// ---------------------------------------------------------------------------
__global__ void detect_kernel(const unsigned short* __restrict__ raw,
                              int* __restrict__ flag)
{
    if (threadIdx.x == 0 && blockIdx.x == 0) {
        int cnt = 0;
        for (int i = 0; i < 64; ++i) {
            unsigned int bits = ((unsigned int)raw[2*i]) << 16;
            float v = __uint_as_float(bits);
            float a = fabsf(v);
            if (a > 1e-4f && a < 50.f) ++cnt;
        }
        *flag = (cnt >= 32) ? 1 : 0;   // 1 = inputs are bf16
    }
}

__global__ void convert_kernel(const void* __restrict__ src,
                               float* __restrict__ dst, int n,
                               const int* __restrict__ flag)
{
    int i = blockIdx.x * 256 + threadIdx.x;
    if (i >= n) return;
    if (*flag)
        dst[i] = __bfloat162float(((const __hip_bfloat16*)src)[i]);
    else
        dst[i] = ((const float*)src)[i];
}

// ---------------------------------------------------------------------------
__device__ __forceinline__ float distt(const float hi[16], float sqi,
                                       const float* __restrict__ hj)
{
    float4 A = *(const float4*)(hj + 0);
    float4 B = *(const float4*)(hj + 4);
    float4 C = *(const float4*)(hj + 8);
    float4 D = *(const float4*)(hj + 12);
    float sqj = hj[16];
    float d0 = hi[0]*A.x;
    float d1 = hi[1]*A.y;
    d0 = fmaf(hi[2],  A.z, d0);  d1 = fmaf(hi[3],  A.w, d1);
    d0 = fmaf(hi[4],  B.x, d0);  d1 = fmaf(hi[5],  B.y, d1);
    d0 = fmaf(hi[6],  B.z, d0);  d1 = fmaf(hi[7],  B.w, d1);
    d0 = fmaf(hi[8],  C.x, d0);  d1 = fmaf(hi[9],  C.y, d1);
    d0 = fmaf(hi[10], C.z, d0);  d1 = fmaf(hi[11], C.w, d1);
    d0 = fmaf(hi[12], D.x, d0);  d1 = fmaf(hi[13], D.y, d1);
    d0 = fmaf(hi[14], D.z, d0);  d1 = fmaf(hi[15], D.w, d1);
    return fmaf(-2.f, d0 + d1, sqi + sqj);
}

#define LOAD_HI(ptr)                                                        \
    float hi[16]; float sqi;                                                \
    {                                                                       \
        const float* _hr = (ptr);                                           \
        float4 A = *(const float4*)(_hr + 0);                               \
        float4 B = *(const float4*)(_hr + 4);                               \
        float4 C = *(const float4*)(_hr + 8);                               \
        float4 D = *(const float4*)(_hr + 12);                              \
        hi[0]=A.x; hi[1]=A.y; hi[2]=A.z; hi[3]=A.w;                         \
        hi[4]=B.x; hi[5]=B.y; hi[6]=B.z; hi[7]=B.w;                         \
        hi[8]=C.x; hi[9]=C.y; hi[10]=C.z; hi[11]=C.w;                       \
        hi[12]=D.x; hi[13]=D.y; hi[14]=D.z; hi[15]=D.w;                     \
        sqi = _hr[16];                                                      \
    }

// ---------------------------------------------------------------------------
__global__ __launch_bounds__(256) void embed_kernel(
    const float* __restrict__ xf, const float* __restrict__ W,
    const float* __restrict__ b, float* __restrict__ h0,
    float4* __restrict__ hT4, float* __restrict__ hTs)
{
    int i = blockIdx.x * 256 + threadIdx.x;
    float x0 = xf[i*3+0], x1 = xf[i*3+1], x2 = xf[i*3+2];
    float* orow = h0 + i * HPS;
    float v[GH];
    float sq = 0.f;
#pragma unroll
    for (int c = 0; c < GH; ++c) {
        float t = b[c];
        t = fmaf(x0, W[0*GH+c], t);
        t = fmaf(x1, W[1*GH+c], t);
        t = fmaf(x2, W[2*GH+c], t);
        t = fmaxf(t, 0.f);
        v[c] = t;
        orow[c] = t;
        sq = fmaf(t, t, sq);
    }
    orow[16] = sq;
    hT4[0*GN + i] = make_float4(v[0],  v[1],  v[2],  v[3]);
    hT4[1*GN + i] = make_float4(v[4],  v[5],  v[6],  v[7]);
    hT4[2*GN + i] = make_float4(v[8],  v[9],  v[10], v[11]);
    hT4[3*GN + i] = make_float4(v[12], v[13], v[14], v[15]);
    hTs[i] = sq;
}

// ---------------------------------------------------------------------------
// Exact kNN: SGPR centers, plane-transposed double-buffered LDS tiles
// (register prefetch, 1 barrier/tile), 2-phase threshold-collect.
__global__ __launch_bounds__(256) void knn13_kernel(
    const float* __restrict__ hp, const float4* __restrict__ hT4,
    const float* __restrict__ hTs,
    int* __restrict__ idxout, int* __restrict__ flags)
{
    __shared__ float lds[LDS_TOT];
    float4*   tA0 = (float4*)lds;               // buf0: 1024 f4
    float*    tS0 = lds + 4096;                 // buf0: 256 sq
    float4*   tA1 = (float4*)(lds + 4352);      // buf1
    float*    tS1 = lds + 8448;
    float*    bufd  = lds + TREG;
    int*      bufj  = (int*)(lds + TREG + RPB*BSTR);
    unsigned* cnt   = (unsigned*)(lds + TREG + 2*RPB*BSTR);
    float*    tauv  = lds + TREG + 2*RPB*BSTR + RPB;
    float*    mrg   = lds + TREG;               // phase-1b overlay (pre-collect)

    const int tid  = threadIdx.x;
    const int wv   = tid >> 6;                  // wave 0..3
    const int lane = tid & 63;
    const int r0   = blockIdx.x * RPB;
    const int rowbase = r0 + wv*4;
    const int wv4 = wv*4;

    if (tid < RPB) cnt[tid] = 0;

    // ---- wave-uniform center rows -> SGPRs
    float hi[4][16], sqi[4];
#pragma unroll
    for (int rr = 0; rr < 4; ++rr) {
        const float* hr = hp + (rowbase + rr) * HPS;
#pragma unroll
        for (int f = 0; f < 16; ++f) hi[rr][f] = rfl(hr[f]);
        sqi[rr] = rfl(hr[16]);
    }

#define DISTC(pA, pS, lc, jglob, dd)                                        \
    {                                                                       \
        float4 A = (pA)[(lc)];                                              \
        float4 B = (pA)[256 + (lc)];                                        \
        float4 C = (pA)[512 + (lc)];                                        \
        float4 D = (pA)[768 + (lc)];                                        \
        float sqj = (pS)[(lc)];                                             \
        unsigned u = (unsigned)((jglob) - rowbase);                         \
        _Pragma("unroll")                                                   \
        for (int rr = 0; rr < 4; ++rr) {                                    \
            float d0 = hi[rr][0]*A.x;                                       \
            float d1 = hi[rr][1]*A.y;                                       \
            d0 = fmaf(hi[rr][2],  A.z, d0);  d1 = fmaf(hi[rr][3],  A.w, d1);\
            d0 = fmaf(hi[rr][4],  B.x, d0);  d1 = fmaf(hi[rr][5],  B.y, d1);\
            d0 = fmaf(hi[rr][6],  B.z, d0);  d1 = fmaf(hi[rr][7],  B.w, d1);\
            d0 = fmaf(hi[rr][8],  C.x, d0);  d1 = fmaf(hi[rr][9],  C.y, d1);\
            d0 = fmaf(hi[rr][10], C.z, d0);  d1 = fmaf(hi[rr][11], C.w, d1);\
            d0 = fmaf(hi[rr][12], D.x, d0);  d1 = fmaf(hi[rr][13], D.y, d1);\
            d0 = fmaf(hi[rr][14], D.z, d0);  d1 = fmaf(hi[rr][15], D.w, d1);\
            float d = fmaf(-2.f, d0 + d1, sqi[rr] + sqj);                   \
            dd[rr] = (u == (unsigned)rr) ? INFF : d;                        \
        }                                                                   \
    }

    float4* cA = tA0; float* cS = tS0;
    float4* nA = tA1; float* nS = tS1;

    // ---- phase 1: sample every 4th column; branchless per-(lane,row) top-2
    float m1[4], m2[4];
#pragma unroll
    for (int rr = 0; rr < 4; ++rr) { m1[rr] = INFF; m2[rr] = INFF; }
    {
        float4 ra0, ra1, ra2, ra3; float rs;
        int jc = 4*tid;
        ra0 = hT4[jc]; ra1 = hT4[GN + jc]; ra2 = hT4[2*GN + jc];
        ra3 = hT4[3*GN + jc]; rs = hTs[jc];
        cA[tid] = ra0; cA[256+tid] = ra1; cA[512+tid] = ra2; cA[768+tid] = ra3;
        cS[tid] = rs;
        for (int k = 0; k < 16; ++k) {
            __syncthreads();
            if (k + 1 < 16) {
                jc = 4*((k+1)*256 + tid);
                ra0 = hT4[jc]; ra1 = hT4[GN + jc]; ra2 = hT4[2*GN + jc];
                ra3 = hT4[3*GN + jc]; rs = hTs[jc];
            }
#pragma unroll
            for (int cc = 0; cc < 4; ++cc) {
                const int lc = lane + 64*cc;
                const int j = 4*(k*256 + lc);
                float dd[4];
                DISTC(cA, cS, lc, j, dd);
#pragma unroll
                for (int rr = 0; rr < 4; ++rr) {
                    float h2 = fmaxf(m1[rr], dd[rr]);
                    m1[rr] = fminf(m1[rr], dd[rr]);
                    m2[rr] = fminf(m2[rr], h2);
                }
            }
            if (k + 1 < 16) {
                nA[tid] = ra0; nA[256+tid] = ra1; nA[512+tid] = ra2;
                nA[768+tid] = ra3; nS[tid] = rs;
            }
            float4* t4 = cA; cA = nA; nA = t4;
            float*  ts = cS; cS = nS; nS = ts;
        }
    }
    __syncthreads();
#pragma unroll
    for (int rr = 0; rr < 4; ++rr) {
        mrg[(wv4+rr)*MSTR + lane*2 + 0] = m1[rr];
        mrg[(wv4+rr)*MSTR + lane*2 + 1] = m2[rr];
    }
    __syncthreads();

    // ---- phase 1b: per-row merge (16 lanes/row): tau = 16th smallest sample
    const int mr = tid >> 4, g = tid & 15;
    {
        float sv[8];
        float4 u0 = *(const float4*)(mrg + mr*MSTR + g*8);
        float4 u1 = *(const float4*)(mrg + mr*MSTR + g*8 + 4);
        sv[0]=u0.x; sv[1]=u0.y; sv[2]=u0.z; sv[3]=u0.w;
        sv[4]=u1.x; sv[5]=u1.y; sv[6]=u1.z; sv[7]=u1.w;
        float tv = INFF;
#pragma unroll
        for (int k = 0; k < 16; ++k) {
            float md = sv[0]; int ms = 0;
#pragma unroll
            for (int e = 1; e < 8; ++e) { bool cs = (sv[e] < md); md = cs ? sv[e] : md; ms = cs ? e : ms; }
            float rv = md; int rl = g;
#pragma unroll
            for (int mm = 1; mm <= 8; mm <<= 1) {
                float ov = __shfl_xor(rv, mm, 16);
                int   ol = __shfl_xor(rl, mm, 16);
                bool cs = (ov < rv) || (ov == rv && ol < rl);
                rv = cs ? ov : rv; rl = cs ? ol : rl;
            }
            tv = rv;
            if (rl == g) {
#pragma unroll
                for (int e = 0; e < 8; ++e) if (e == ms) sv[e] = INFF;
            }
        }
        if (g == 0) tauv[mr] = tv;
    }
    __syncthreads();

    float tr[4];
#pragma unroll
    for (int rr = 0; rr < 4; ++rr) tr[rr] = rfl(tauv[wv4+rr]);

    // ---- phase 2: full scan; collect d <= tau (identical dd chain ->
    // sampled qualifiers re-qualify bit-identically -> cnt >= 16)
    {
        float4 ra0, ra1, ra2, ra3; float rs;
        ra0 = hT4[tid]; ra1 = hT4[GN + tid]; ra2 = hT4[2*GN + tid];
        ra3 = hT4[3*GN + tid]; rs = hTs[tid];
        cA[tid] = ra0; cA[256+tid] = ra1; cA[512+tid] = ra2; cA[768+tid] = ra3;
        cS[tid] = rs;
        for (int k = 0; k < GN/256; ++k) {
            __syncthreads();
            if (k + 1 < GN/256) {
                const int jc = (k+1)*256 + tid;
                ra0 = hT4[jc]; ra1 = hT4[GN + jc]; ra2 = hT4[2*GN + jc];
                ra3 = hT4[3*GN + jc]; rs = hTs[jc];
            }
#pragma unroll
            for (int cc = 0; cc < 4; ++cc) {
                const int lc = lane + 64*cc;
                const int j = k*256 + lc;
                float dd[4];
                DISTC(cA, cS, lc, j, dd);
                bool p0 = dd[0] <= tr[0], p1 = dd[1] <= tr[1];
                bool p2 = dd[2] <= tr[2], p3 = dd[3] <= tr[3];
                if (p0 | p1 | p2 | p3) {
#pragma unroll
                    for (int rr = 0; rr < 4; ++rr) {
                        if (dd[rr] <= tr[rr]) {
                            unsigned pos = atomicAdd(&cnt[wv4+rr], 1u);
                            if (pos < CAP) {
                                bufd[(wv4+rr)*BSTR + pos] = dd[rr];
                                bufj[(wv4+rr)*BSTR + pos] = j;
                            }
                        }
                    }
                }
            }
            if (k + 1 < GN/256) {
                nA[tid] = ra0; nA[256+tid] = ra1; nA[512+tid] = ra2;
                nA[768+tid] = ra3; nS[tid] = rs;
            }
            float4* t4 = cA; cA = nA; nA = t4;
            float*  ts = cS; cS = nS; nS = ts;
        }
    }
    __syncthreads();

    // ---- phase 3: exact top-16 per row (16 lanes x 6 entries), (d,j) order
    {
        const unsigned c2  = cnt[mr];
        const unsigned lim = c2 < CAP ? c2 : CAP;
        float sd[6]; int sj[6];
#pragma unroll
        for (int e = 0; e < 6; ++e) {
            unsigned p = (unsigned)g + 16u*e;
            bool v = p < lim;
            sd[e] = v ? bufd[mr*BSTR + p] : INFF;
            sj[e] = v ? bufj[mr*BSTR + p] : 0x7fffffff;
        }
        const int rowg = r0 + mr;
#pragma unroll
        for (int k = 0; k < GK; ++k) {
            float md = sd[0]; int mj = sj[0]; int ms = 0;
#pragma unroll
            for (int e = 1; e < 6; ++e) {
                bool cs = (sd[e] < md) || (sd[e] == md && sj[e] < mj);
                md = cs ? sd[e] : md; mj = cs ? sj[e] : mj; ms = cs ? e : ms;
            }
            float rd = md; int rj = mj;
#pragma unroll
            for (int mm = 1; mm <= 8; mm <<= 1) {
                float od = __shfl_xor(rd, mm, 16);
                int   oj = __shfl_xor(rj, mm, 16);
                bool cs = (od < rd) || (od == rd && oj < rj);
                rd = cs ? od : rd; rj = cs ? oj : rj;
            }
            if (g == 0) idxout[rowg*GK + k] = rj;
            if (rd == md && rj == mj) {
#pragma unroll
                for (int e = 0; e < 6; ++e) if (e == ms) { sd[e] = INFF; sj[e] = 0x7fffffff; }
            }
        }
        if (g == 0) flags[rowg] = (c2 > CAP || c2 < 16u) ? 1 : 0;
    }
#undef DISTC
}

// ---------------------------------------------------------------------------
// Exact full-scan fallback for flagged rows (1 wave/block; slow-but-correct).
__global__ __launch_bounds__(64) void rescue_kernel(
    const float* __restrict__ hp, const int* __restrict__ flags,
    int* __restrict__ idxout)
{
    const int lane = threadIdx.x;
    const int r0 = blockIdx.x * RPB;
    int f = (lane < RPB) ? flags[r0 + lane] : 0;
    if (__ballot(f != 0) == 0ull) return;
    for (int rr = 0; rr < RPB; ++rr) {
        if (flags[r0 + rr] == 0) continue;
        const int row = r0 + rr;
        LOAD_HI(hp + row * HPS);
        float topd[GK]; int topi[GK];
#pragma unroll
        for (int s = 0; s < GK; ++s) { topd[s] = INFF; topi[s] = -1; }
        float mx = INFF; int mxs = 0;
        for (int s = 0; s < GN/64; ++s) {
            int j = lane + (s << 6);
            float d = distt(hi, sqi, hp + j * HPS);
            if (j == row) d = INFF;
            if (d < mx) {
#pragma unroll
                for (int e = 0; e < GK; ++e) { bool cs = (e == mxs); topd[e] = cs ? d : topd[e]; topi[e] = cs ? j : topi[e]; }
                mx = topd[0]; mxs = 0;
#pragma unroll
                for (int e = 1; e < GK; ++e) { bool cs = (topd[e] >= mx); mx = cs ? topd[e] : mx; mxs = cs ? e : mxs; }
            }
        }
#pragma unroll
        for (int t = 0; t < GK; ++t) {
            float md = topd[0]; int mj = topi[0]; int ms = 0;
#pragma unroll
            for (int e = 1; e < GK; ++e) {
                bool cs = (topd[e] < md) || (topd[e] == md && topi[e] < mj);
                md = cs ? topd[e] : md; mj = cs ? topi[e] : mj; ms = cs ? e : ms;
            }
            float rd = md; int rj = mj;
#pragma unroll
            for (int m = 1; m <= 32; m <<= 1) {
                float od = __shfl_xor(rd, m, 64);
                int   oj = __shfl_xor(rj, m, 64);
                bool cs = (od < rd) || (od == rd && oj < rj);
                rd = cs ? od : rd; rj = cs ? oj : rj;
            }
            if (lane == 0) idxout[row*GK + t] = rj;
            if (rd == md && rj == mj) {
#pragma unroll
                for (int e = 0; e < GK; ++e) if (e == ms) { topd[e] = INFF; topi[e] = 0x7fffffff; }
            }
        }
    }
}

// ---------------------------------------------------------------------------
__global__ __launch_bounds__(256) void edgeconv_kernel(
    const float* __restrict__ hin, const int* __restrict__ idx,
    const float* __restrict__ W1, const float* __restrict__ b1,
    const float* __restrict__ W2, const float* __restrict__ b2,
    float* __restrict__ hout, float4* __restrict__ hT4,
    float* __restrict__ hTs)
{
    __shared__ float sW1[2*GH*GH], sW2[GH*GH], sb1[GH], sb2[GH];
    const int tid = threadIdx.x;
    for (int t = tid; t < 2*GH*GH; t += 256) sW1[t] = W1[t];
    for (int t = tid; t < GH*GH;  t += 256) sW2[t] = W2[t];
    if (tid < GH) { sb1[tid] = b1[tid]; sb2[tid] = b2[tid]; }
    __syncthreads();

    const int t4 = tid & 3;
    const int i = blockIdx.x * 64 + (tid >> 2);

    LOAD_HI(hin + i * HPS);
    (void)sqi;
    float ci[GH];
#pragma unroll
    for (int c = 0; c < GH; ++c) {
        float s = sb1[c];
#pragma unroll
        for (int d = 0; d < GH; ++d) s = fmaf(hi[d], sW1[d*GH+c], s);
        ci[c] = s;
    }
    float acc[GH];
#pragma unroll
    for (int c = 0; c < GH; ++c) acc[c] = 0.f;

    const int4 jj = *(const int4*)(idx + i*GK + t4*4);
    const int js[4] = { jj.x, jj.y, jj.z, jj.w };
#pragma unroll
    for (int nn = 0; nn < 4; ++nn) {
        const int j = js[nn];
        float dj[GH];
        {
            const float* hv = hin + j * HPS;
            float4 A = *(const float4*)(hv + 0);
            float4 B = *(const float4*)(hv + 4);
            float4 C = *(const float4*)(hv + 8);
            float4 D = *(const float4*)(hv + 12);
            dj[0]=A.x-hi[0]; dj[1]=A.y-hi[1]; dj[2]=A.z-hi[2]; dj[3]=A.w-hi[3];
            dj[4]=B.x-hi[4]; dj[5]=B.y-hi[5]; dj[6]=B.z-hi[6]; dj[7]=B.w-hi[7];
            dj[8]=C.x-hi[8]; dj[9]=C.y-hi[9]; dj[10]=C.z-hi[10]; dj[11]=C.w-hi[11];
            dj[12]=D.x-hi[12]; dj[13]=D.y-hi[13]; dj[14]=D.z-hi[14]; dj[15]=D.w-hi[15];
        }
        float msg[GH];
#pragma unroll
        for (int c = 0; c < GH; ++c) {
            float s = ci[c];
#pragma unroll
            for (int d = 0; d < GH; ++d) s = fmaf(dj[d], sW1[(GH+d)*GH+c], s);
            msg[c] = fmaxf(s, 0.f);
        }
#pragma unroll
        for (int c2 = 0; c2 < GH; ++c2) {
            float s = acc[c2];
#pragma unroll
            for (int c = 0; c < GH; ++c) s = fmaf(msg[c], sW2[c*GH+c2], s);
            acc[c2] = s;
        }
    }
#pragma unroll
    for (int c = 0; c < GH; ++c) {
        acc[c] += __shfl_xor(acc[c], 1);
        acc[c] += __shfl_xor(acc[c], 2);
    }
    if (t4 == 0) {
        float* orow = hout + i * HPS;
        float v[GH];
        float sq = 0.f;
#pragma unroll
        for (int c = 0; c < GH; ++c) {
            float t = acc[c] * (1.f/16.f) + sb2[c];
            v[c] = t;
            orow[c] = t;
            sq = fmaf(t, t, sq);
        }
        orow[16] = sq;
        hT4[0*GN + i] = make_float4(v[0],  v[1],  v[2],  v[3]);
        hT4[1*GN + i] = make_float4(v[4],  v[5],  v[6],  v[7]);
        hT4[2*GN + i] = make_float4(v[8],  v[9],  v[10], v[11]);
        hT4[3*GN + i] = make_float4(v[12], v[13], v[14], v[15]);
        hTs[i] = sq;
    }
}

// ---------------------------------------------------------------------------
__global__ __launch_bounds__(256) void out_kernel(
    const float* __restrict__ hbase, const float* __restrict__ W,
    const float* __restrict__ b, void* __restrict__ out,
    const int* __restrict__ flag)
{
    int i = blockIdx.x * 256 + threadIdx.x;
    float a0 = b[0], a1 = b[1], a2 = b[2];
#pragma unroll
    for (int l = 0; l < GL; ++l) {
        const float* hp = hbase + l * GN * HPS + i * HPS;
#pragma unroll
        for (int c = 0; c < GH; ++c) {
            const float v = hp[c];
            const float* wr = W + (l * GH + c) * 3;
            a0 = fmaf(v, wr[0], a0);
            a1 = fmaf(v, wr[1], a1);
            a2 = fmaf(v, wr[2], a2);
        }
    }
    if (*flag) {
        __hip_bfloat16* o = (__hip_bfloat16*)out;
        o[i*3+0] = __float2bfloat16(a0);
        o[i*3+1] = __float2bfloat16(a1);
        o[i*3+2] = __float2bfloat16(a2);
    } else {
        float* o = (float*)out;
        o[i*3+0] = a0; o[i*3+1] = a1; o[i*3+2] = a2;
    }
}

// ---------------------------------------------------------------------------
extern "C" void kernel_launch(void* const* d_in, const int* in_sizes, int n_in,
                              void* d_out, int out_size, void* d_ws, size_t ws_size,
                              hipStream_t stream)
{
    float* wsf  = (float*)d_ws;
    int* idxb   = (int*)(wsf + OFF_IDX);
    int* flagsb = (int*)(wsf + OFF_FLAGS);
    int* dflag  = (int*)(wsf + OFF_DFLAG);
    float4* hT4 = (float4*)(wsf + OFF_HT);
    float*  hTs = wsf + OFF_HTS;

    detect_kernel<<<1, 64, 0, stream>>>((const unsigned short*)d_in[0], dflag);

    const int segoff[9] = {OFF_XF, OFF_EMBW, OFF_EMBB, OFF_W1, OFF_B1,
                           OFF_W2, OFF_B2, OFF_OW, OFF_OB};
    const int segn[9]   = {GN*3, 3*GH, GH, GL*2*GH*GH, GL*GH,
                           GL*GH*GH, GL*GH, GL*GH*3, 3};
    for (int s = 0; s < 9; ++s)
        convert_kernel<<<(segn[s] + 255)/256, 256, 0, stream>>>(
            d_in[s], wsf + segoff[s], segn[s], dflag);

    embed_kernel<<<GN/256, 256, 0, stream>>>(
        wsf + OFF_XF, wsf + OFF_EMBW, wsf + OFF_EMBB, wsf + OFF_H, hT4, hTs);

    for (int l = 0; l < GL; ++l) {
        const float* hin = wsf + OFF_H + l*GN*HPS;
        float* hout      = wsf + OFF_H + (l+1)*GN*HPS;
        knn13_kernel<<<GN/RPB, TPB, 0, stream>>>(hin, hT4, hTs, idxb, flagsb);
        rescue_kernel<<<GN/RPB, 64, 0, stream>>>(hin, flagsb, idxb);
        edgeconv_kernel<<<GN/64, 256, 0, stream>>>(hin, idxb,
            wsf + OFF_W1 + l*2*GH*GH, wsf + OFF_B1 + l*GH,
            wsf + OFF_W2 + l*GH*GH,  wsf + OFF_B2 + l*GH, hout, hT4, hTs);
    }

    out_kernel<<<GN/256, 256, 0, stream>>>(
        wsf + OFF_H + GN*HPS, wsf + OFF_OW, wsf + OFF_OB, d_out, dflag);
}

// Round 14
// 1565.663 us; speedup vs baseline: 2.2707x; 2.2707x over previous
//
#include <hip/hip_runtime.h>
#include <hip/hip_bf16.h>

#define GN 16384
#define GH 16
#define GK 16
#define GL 4
#define HPS 20            // padded h row: 16 features + sq + 3 pad (80 B)

#define TPB 256           // knn block: 4 waves x 4 rows each = 16 rows
#define RPB 16            // rows per knn block
#define CAP 224           // collect capacity per row (E[cnt]=64, ~10 sigma)
#define BSTR 225          // index buffer row stride (ints)
#define MSTR 132          // phase-1 merge row stride (128 vals + pad)
// LDS floats: 2 tile-bufs (1024 f4 + 256 sq each) + bufj + cnt + tau
#define TREG  (2*4096 + 2*256)                 // 8704
#define LDS_TOT (TREG + RPB*BSTR + 2*RPB)      // 12336 floats = 49.3 KB

#define INFF __builtin_inff()

// workspace float-offsets
#define OFF_H     0
#define OFF_IDX   (5*GN*HPS)
#define OFF_FLAGS (OFF_IDX + GN*GK)
#define OFF_XF    (OFF_FLAGS + GN)
#define OFF_EMBW  (OFF_XF + GN*3)
#define OFF_EMBB  (OFF_EMBW + 3*GH)
#define OFF_W1    (OFF_EMBB + GH)
#define OFF_B1    (OFF_W1 + GL*2*GH*GH)
#define OFF_W2    (OFF_B1 + GL*GH)
#define OFF_B2    (OFF_W2 + GL*GH*GH)
#define OFF_OW    (OFF_B2 + GL*GH)
#define OFF_OB    (OFF_OW + GL*GH*3)
#define OFF_DFLAG (OFF_OB + 4)
#define OFF_HT    (OFF_DFLAG + 8)     // 4 float4-planes (GN*16 f) + sq plane (GN f)
#define OFF_HTS   (OFF_HT + GN*16)

// ---------------------------------------------------------------------------
__device__ __forceinline__ float rfl(float x)
{
    return __uint_as_float(__builtin_amdgcn_readfirstlane(__float_as_uint(x)));
}

// ---------------------------------------------------------------------------
__global__ void detect_kernel(const unsigned short* __restrict__ raw,
                              int* __restrict__ flag)
{
    if (threadIdx.x == 0 && blockIdx.x == 0) {
        int cnt = 0;
        for (int i = 0; i < 64; ++i) {
            unsigned int bits = ((unsigned int)raw[2*i]) << 16;
            float v = __uint_as_float(bits);
            float a = fabsf(v);
            if (a > 1e-4f && a < 50.f) ++cnt;
        }
        *flag = (cnt >= 32) ? 1 : 0;   // 1 = inputs are bf16
    }
}

__global__ void convert_kernel(const void* __restrict__ src,
                               float* __restrict__ dst, int n,
                               const int* __restrict__ flag)
{
    int i = blockIdx.x * 256 + threadIdx.x;
    if (i >= n) return;
    if (*flag)
        dst[i] = __bfloat162float(((const __hip_bfloat16*)src)[i]);
    else
        dst[i] = ((const float*)src)[i];
}

// ---------------------------------------------------------------------------
__device__ __forceinline__ float distt(const float hi[16], float sqi,
                                       const float* __restrict__ hj)
{
    float4 A = *(const float4*)(hj + 0);
    float4 B = *(const float4*)(hj + 4);
    float4 C = *(const float4*)(hj + 8);
    float4 D = *(const float4*)(hj + 12);
    float sqj = hj[16];
    float d0 = hi[0]*A.x;
    float d1 = hi[1]*A.y;
    d0 = fmaf(hi[2],  A.z, d0);  d1 = fmaf(hi[3],  A.w, d1);
    d0 = fmaf(hi[4],  B.x, d0);  d1 = fmaf(hi[5],  B.y, d1);
    d0 = fmaf(hi[6],  B.z, d0);  d1 = fmaf(hi[7],  B.w, d1);
    d0 = fmaf(hi[8],  C.x, d0);  d1 = fmaf(hi[9],  C.y, d1);
    d0 = fmaf(hi[10], C.z, d0);  d1 = fmaf(hi[11], C.w, d1);
    d0 = fmaf(hi[12], D.x, d0);  d1 = fmaf(hi[13], D.y, d1);
    d0 = fmaf(hi[14], D.z, d0);  d1 = fmaf(hi[15], D.w, d1);
    return fmaf(-2.f, d0 + d1, sqi + sqj);
}

#define LOAD_HI(ptr)                                                        \
    float hi[16]; float sqi;                                                \
    {                                                                       \
        const float* _hr = (ptr);                                           \
        float4 A = *(const float4*)(_hr + 0);                               \
        float4 B = *(const float4*)(_hr + 4);                               \
        float4 C = *(const float4*)(_hr + 8);                               \
        float4 D = *(const float4*)(_hr + 12);                              \
        hi[0]=A.x; hi[1]=A.y; hi[2]=A.z; hi[3]=A.w;                         \
        hi[4]=B.x; hi[5]=B.y; hi[6]=B.z; hi[7]=B.w;                         \
        hi[8]=C.x; hi[9]=C.y; hi[10]=C.z; hi[11]=C.w;                       \
        hi[12]=D.x; hi[13]=D.y; hi[14]=D.z; hi[15]=D.w;                     \
        sqi = _hr[16];                                                      \
    }

// ---------------------------------------------------------------------------
__global__ __launch_bounds__(256) void embed_kernel(
    const float* __restrict__ xf, const float* __restrict__ W,
    const float* __restrict__ b, float* __restrict__ h0,
    float4* __restrict__ hT4, float* __restrict__ hTs)
{
    int i = blockIdx.x * 256 + threadIdx.x;
    float x0 = xf[i*3+0], x1 = xf[i*3+1], x2 = xf[i*3+2];
    float* orow = h0 + i * HPS;
    float v[GH];
    float sq = 0.f;
#pragma unroll
    for (int c = 0; c < GH; ++c) {
        float t = b[c];
        t = fmaf(x0, W[0*GH+c], t);
        t = fmaf(x1, W[1*GH+c], t);
        t = fmaf(x2, W[2*GH+c], t);
        t = fmaxf(t, 0.f);
        v[c] = t;
        orow[c] = t;
        sq = fmaf(t, t, sq);
    }
    orow[16] = sq;
    hT4[0*GN + i] = make_float4(v[0],  v[1],  v[2],  v[3]);
    hT4[1*GN + i] = make_float4(v[4],  v[5],  v[6],  v[7]);
    hT4[2*GN + i] = make_float4(v[8],  v[9],  v[10], v[11]);
    hT4[3*GN + i] = make_float4(v[12], v[13], v[14], v[15]);
    hTs[i] = sq;
}

// ---------------------------------------------------------------------------
// Exact kNN: SGPR centers, plane-transposed double-buffered LDS tiles
// (register prefetch, 1 barrier/tile), 2-phase threshold-collect with
// index-only buffer; phase-3 recomputes d bit-identically for selection.
__global__ __launch_bounds__(256) void knn14_kernel(
    const float* __restrict__ hp, const float4* __restrict__ hT4,
    const float* __restrict__ hTs,
    int* __restrict__ idxout, int* __restrict__ flags)
{
    __shared__ float lds[LDS_TOT];
    float4*   tA0 = (float4*)lds;               // buf0: 1024 f4
    float*    tS0 = lds + 4096;                 // buf0: 256 sq
    float4*   tA1 = (float4*)(lds + 4352);      // buf1
    float*    tS1 = lds + 8448;
    int*      bufj  = (int*)(lds + TREG);
    unsigned* cnt   = (unsigned*)(lds + TREG + RPB*BSTR);
    float*    tauv  = lds + TREG + RPB*BSTR + RPB;
    float*    mrg   = lds + TREG;               // phase-1b overlay (pre-collect)

    const int tid  = threadIdx.x;
    const int wv   = tid >> 6;                  // wave 0..3
    const int lane = tid & 63;
    const int r0   = blockIdx.x * RPB;
    const int rowbase = r0 + wv*4;
    const int wv4 = wv*4;

    if (tid < RPB) cnt[tid] = 0;

    // ---- wave-uniform center rows -> SGPRs
    float hi[4][16], sqi[4];
#pragma unroll
    for (int rr = 0; rr < 4; ++rr) {
        const float* hr = hp + (rowbase + rr) * HPS;
#pragma unroll
        for (int f = 0; f < 16; ++f) hi[rr][f] = rfl(hr[f]);
        sqi[rr] = rfl(hr[16]);
    }

#define DISTC(pA, pS, lc, jglob, dd)                                        \
    {                                                                       \
        float4 A = (pA)[(lc)];                                              \
        float4 B = (pA)[256 + (lc)];                                        \
        float4 C = (pA)[512 + (lc)];                                        \
        float4 D = (pA)[768 + (lc)];                                        \
        float sqj = (pS)[(lc)];                                             \
        unsigned u = (unsigned)((jglob) - rowbase);                         \
        _Pragma("unroll")                                                   \
        for (int rr = 0; rr < 4; ++rr) {                                    \
            float d0 = hi[rr][0]*A.x;                                       \
            float d1 = hi[rr][1]*A.y;                                       \
            d0 = fmaf(hi[rr][2],  A.z, d0);  d1 = fmaf(hi[rr][3],  A.w, d1);\
            d0 = fmaf(hi[rr][4],  B.x, d0);  d1 = fmaf(hi[rr][5],  B.y, d1);\
            d0 = fmaf(hi[rr][6],  B.z, d0);  d1 = fmaf(hi[rr][7],  B.w, d1);\
            d0 = fmaf(hi[rr][8],  C.x, d0);  d1 = fmaf(hi[rr][9],  C.y, d1);\
            d0 = fmaf(hi[rr][10], C.z, d0);  d1 = fmaf(hi[rr][11], C.w, d1);\
            d0 = fmaf(hi[rr][12], D.x, d0);  d1 = fmaf(hi[rr][13], D.y, d1);\
            d0 = fmaf(hi[rr][14], D.z, d0);  d1 = fmaf(hi[rr][15], D.w, d1);\
            float d = fmaf(-2.f, d0 + d1, sqi[rr] + sqj);                   \
            dd[rr] = (u == (unsigned)rr) ? INFF : d;                        \
        }                                                                   \
    }

    float4* cA = tA0; float* cS = tS0;
    float4* nA = tA1; float* nS = tS1;

    // ---- phase 1: sample every 4th column; branchless per-(lane,row) top-2
    float m1[4], m2[4];
#pragma unroll
    for (int rr = 0; rr < 4; ++rr) { m1[rr] = INFF; m2[rr] = INFF; }
    {
        float4 ra0, ra1, ra2, ra3; float rs;
        int jc = 4*tid;
        ra0 = hT4[jc]; ra1 = hT4[GN + jc]; ra2 = hT4[2*GN + jc];
        ra3 = hT4[3*GN + jc]; rs = hTs[jc];
        cA[tid] = ra0; cA[256+tid] = ra1; cA[512+tid] = ra2; cA[768+tid] = ra3;
        cS[tid] = rs;
        for (int k = 0; k < 16; ++k) {
            __syncthreads();
            if (k + 1 < 16) {
                jc = 4*((k+1)*256 + tid);
                ra0 = hT4[jc]; ra1 = hT4[GN + jc]; ra2 = hT4[2*GN + jc];
                ra3 = hT4[3*GN + jc]; rs = hTs[jc];
            }
#pragma unroll
            for (int cc = 0; cc < 4; ++cc) {
                const int lc = lane + 64*cc;
                const int j = 4*(k*256 + lc);
                float dd[4];
                DISTC(cA, cS, lc, j, dd);
#pragma unroll
                for (int rr = 0; rr < 4; ++rr) {
                    float h2 = fmaxf(m1[rr], dd[rr]);
                    m1[rr] = fminf(m1[rr], dd[rr]);
                    m2[rr] = fminf(m2[rr], h2);
                }
            }
            if (k + 1 < 16) {
                nA[tid] = ra0; nA[256+tid] = ra1; nA[512+tid] = ra2;
                nA[768+tid] = ra3; nS[tid] = rs;
            }
            float4* t4 = cA; cA = nA; nA = t4;
            float*  ts = cS; cS = nS; nS = ts;
        }
    }
    __syncthreads();
#pragma unroll
    for (int rr = 0; rr < 4; ++rr) {
        mrg[(wv4+rr)*MSTR + lane*2 + 0] = m1[rr];
        mrg[(wv4+rr)*MSTR + lane*2 + 1] = m2[rr];
    }
    __syncthreads();

    // ---- phase 1b: per-row merge (16 lanes/row): tau = 16th smallest sample
    const int mr = tid >> 4, g = tid & 15;
    {
        float sv[8];
        float4 u0 = *(const float4*)(mrg + mr*MSTR + g*8);
        float4 u1 = *(const float4*)(mrg + mr*MSTR + g*8 + 4);
        sv[0]=u0.x; sv[1]=u0.y; sv[2]=u0.z; sv[3]=u0.w;
        sv[4]=u1.x; sv[5]=u1.y; sv[6]=u1.z; sv[7]=u1.w;
        float tv = INFF;
#pragma unroll
        for (int k = 0; k < 16; ++k) {
            float md = sv[0]; int ms = 0;
#pragma unroll
            for (int e = 1; e < 8; ++e) { bool cs = (sv[e] < md); md = cs ? sv[e] : md; ms = cs ? e : ms; }
            float rv = md; int rl = g;
#pragma unroll
            for (int mm = 1; mm <= 8; mm <<= 1) {
                float ov = __shfl_xor(rv, mm, 16);
                int   ol = __shfl_xor(rl, mm, 16);
                bool cs = (ov < rv) || (ov == rv && ol < rl);
                rv = cs ? ov : rv; rl = cs ? ol : rl;
            }
            tv = rv;
            if (rl == g) {
#pragma unroll
                for (int e = 0; e < 8; ++e) if (e == ms) sv[e] = INFF;
            }
        }
        if (g == 0) tauv[mr] = tv;
    }
    __syncthreads();

    float tr[4];
#pragma unroll
    for (int rr = 0; rr < 4; ++rr) tr[rr] = rfl(tauv[wv4+rr]);

    // ---- phase 2: full scan; collect j where d <= tau (identical dd chain ->
    // sampled qualifiers re-qualify bit-identically -> cnt >= 16)
    {
        float4 ra0, ra1, ra2, ra3; float rs;
        ra0 = hT4[tid]; ra1 = hT4[GN + tid]; ra2 = hT4[2*GN + tid];
        ra3 = hT4[3*GN + tid]; rs = hTs[tid];
        cA[tid] = ra0; cA[256+tid] = ra1; cA[512+tid] = ra2; cA[768+tid] = ra3;
        cS[tid] = rs;
        for (int k = 0; k < GN/256; ++k) {
            __syncthreads();
            if (k + 1 < GN/256) {
                const int jc = (k+1)*256 + tid;
                ra0 = hT4[jc]; ra1 = hT4[GN + jc]; ra2 = hT4[2*GN + jc];
                ra3 = hT4[3*GN + jc]; rs = hTs[jc];
            }
#pragma unroll
            for (int cc = 0; cc < 4; ++cc) {
                const int lc = lane + 64*cc;
                const int j = k*256 + lc;
                float dd[4];
                DISTC(cA, cS, lc, j, dd);
                bool p0 = dd[0] <= tr[0], p1 = dd[1] <= tr[1];
                bool p2 = dd[2] <= tr[2], p3 = dd[3] <= tr[3];
                if (p0 | p1 | p2 | p3) {
#pragma unroll
                    for (int rr = 0; rr < 4; ++rr) {
                        if (dd[rr] <= tr[rr]) {
                            unsigned pos = atomicAdd(&cnt[wv4+rr], 1u);
                            if (pos < CAP) bufj[(wv4+rr)*BSTR + pos] = j;
                        }
                    }
                }
            }
            if (k + 1 < GN/256) {
                nA[tid] = ra0; nA[256+tid] = ra1; nA[512+tid] = ra2;
                nA[768+tid] = ra3; nS[tid] = rs;
            }
            float4* t4 = cA; cA = nA; nA = t4;
            float*  ts = cS; cS = nS; nS = ts;
        }
    }
    __syncthreads();

    // ---- phase 3: recompute d (bit-identical distt chain) + exact top-16
    // per row (16 lanes x 14 entries), (d,j) lexicographic order
    {
        const unsigned c2  = cnt[mr];
        const unsigned lim = c2 < CAP ? c2 : CAP;
        LOAD_HI(hp + (r0 + mr)*HPS);
        float sd[14]; int sj[14];
#pragma unroll
        for (int e = 0; e < 14; ++e) {
            unsigned p = (unsigned)g + 16u*e;
            if (p < lim) {
                int j = bufj[mr*BSTR + p];
                sj[e] = j;
                sd[e] = distt(hi, sqi, hp + j*HPS);
            } else { sd[e] = INFF; sj[e] = 0x7fffffff; }
        }
        const int rowg = r0 + mr;
#pragma unroll
        for (int k = 0; k < GK; ++k) {
            float md = sd[0]; int mj = sj[0]; int ms = 0;
#pragma unroll
            for (int e = 1; e < 14; ++e) {
                bool cs = (sd[e] < md) || (sd[e] == md && sj[e] < mj);
                md = cs ? sd[e] : md; mj = cs ? sj[e] : mj; ms = cs ? e : ms;
            }
            float rd = md; int rj = mj;
#pragma unroll
            for (int mm = 1; mm <= 8; mm <<= 1) {
                float od = __shfl_xor(rd, mm, 16);
                int   oj = __shfl_xor(rj, mm, 16);
                bool cs = (od < rd) || (od == rd && oj < rj);
                rd = cs ? od : rd; rj = cs ? oj : rj;
            }
            if (g == 0) idxout[rowg*GK + k] = rj;
            if (rd == md && rj == mj) {
#pragma unroll
                for (int e = 0; e < 14; ++e) if (e == ms) { sd[e] = INFF; sj[e] = 0x7fffffff; }
            }
        }
        if (g == 0) flags[rowg] = (c2 > CAP || c2 < 16u) ? 1 : 0;
    }
#undef DISTC
}

// ---------------------------------------------------------------------------
// Exact full-scan fallback for flagged rows (4 waves; slow-but-correct).
__global__ __launch_bounds__(256) void rescue_kernel(
    const float* __restrict__ hp, const int* __restrict__ flags,
    int* __restrict__ idxout)
{
    const int lane = threadIdx.x & 63;
    const int ww   = threadIdx.x >> 6;
    const int r0 = blockIdx.x * RPB;
    int f = (lane < RPB) ? flags[r0 + lane] : 0;
    if (__ballot(f != 0) == 0ull) return;
    for (int rr = ww; rr < RPB; rr += 4) {
        if (flags[r0 + rr] == 0) continue;
        const int row = r0 + rr;
        LOAD_HI(hp + row * HPS);
        float topd[GK]; int topi[GK];
#pragma unroll
        for (int s = 0; s < GK; ++s) { topd[s] = INFF; topi[s] = -1; }
        float mx = INFF; int mxs = 0;
        for (int s = 0; s < GN/64; ++s) {
            int j = lane + (s << 6);
            float d = distt(hi, sqi, hp + j * HPS);
            if (j == row) d = INFF;
            if (d < mx) {
#pragma unroll
                for (int e = 0; e < GK; ++e) { bool cs = (e == mxs); topd[e] = cs ? d : topd[e]; topi[e] = cs ? j : topi[e]; }
                mx = topd[0]; mxs = 0;
#pragma unroll
                for (int e = 1; e < GK; ++e) { bool cs = (topd[e] >= mx); mx = cs ? topd[e] : mx; mxs = cs ? e : mxs; }
            }
        }
#pragma unroll
        for (int t = 0; t < GK; ++t) {
            float md = topd[0]; int mj = topi[0]; int ms = 0;
#pragma unroll
            for (int e = 1; e < GK; ++e) {
                bool cs = (topd[e] < md) || (topd[e] == md && topi[e] < mj);
                md = cs ? topd[e] : md; mj = cs ? topi[e] : mj; ms = cs ? e : ms;
            }
            float rd = md; int rj = mj;
#pragma unroll
            for (int m = 1; m <= 32; m <<= 1) {
                float od = __shfl_xor(rd, m, 64);
                int   oj = __shfl_xor(rj, m, 64);
                bool cs = (od < rd) || (od == rd && oj < rj);
                rd = cs ? od : rd; rj = cs ? oj : rj;
            }
            if (lane == 0) idxout[row*GK + t] = rj;
            if (rd == md && rj == mj) {
#pragma unroll
                for (int e = 0; e < GK; ++e) if (e == ms) { topd[e] = INFF; topi[e] = 0x7fffffff; }
            }
        }
    }
}

// ---------------------------------------------------------------------------
__global__ __launch_bounds__(256) void edgeconv_kernel(
    const float* __restrict__ hin, const int* __restrict__ idx,
    const float* __restrict__ W1, const float* __restrict__ b1,
    const float* __restrict__ W2, const float* __restrict__ b2,
    float* __restrict__ hout, float4* __restrict__ hT4,
    float* __restrict__ hTs)
{
    __shared__ float sW1[2*GH*GH], sW2[GH*GH], sb1[GH], sb2[GH];
    const int tid = threadIdx.x;
    for (int t = tid; t < 2*GH*GH; t += 256) sW1[t] = W1[t];
    for (int t = tid; t < GH*GH;  t += 256) sW2[t] = W2[t];
    if (tid < GH) { sb1[tid] = b1[tid]; sb2[tid] = b2[tid]; }
    __syncthreads();

    const int t4 = tid & 3;
    const int i = blockIdx.x * 64 + (tid >> 2);

    LOAD_HI(hin + i * HPS);
    (void)sqi;
    float ci[GH];
#pragma unroll
    for (int c = 0; c < GH; ++c) {
        float s = sb1[c];
#pragma unroll
        for (int d = 0; d < GH; ++d) s = fmaf(hi[d], sW1[d*GH+c], s);
        ci[c] = s;
    }
    float acc[GH];
#pragma unroll
    for (int c = 0; c < GH; ++c) acc[c] = 0.f;

    const int4 jj = *(const int4*)(idx + i*GK + t4*4);
    const int js[4] = { jj.x, jj.y, jj.z, jj.w };
#pragma unroll
    for (int nn = 0; nn < 4; ++nn) {
        const int j = js[nn];
        float dj[GH];
        {
            const float* hv = hin + j * HPS;
            float4 A = *(const float4*)(hv + 0);
            float4 B = *(const float4*)(hv + 4);
            float4 C = *(const float4*)(hv + 8);
            float4 D = *(const float4*)(hv + 12);
            dj[0]=A.x-hi[0]; dj[1]=A.y-hi[1]; dj[2]=A.z-hi[2]; dj[3]=A.w-hi[3];
            dj[4]=B.x-hi[4]; dj[5]=B.y-hi[5]; dj[6]=B.z-hi[6]; dj[7]=B.w-hi[7];
            dj[8]=C.x-hi[8]; dj[9]=C.y-hi[9]; dj[10]=C.z-hi[10]; dj[11]=C.w-hi[11];
            dj[12]=D.x-hi[12]; dj[13]=D.y-hi[13]; dj[14]=D.z-hi[14]; dj[15]=D.w-hi[15];
        }
        float msg[GH];
#pragma unroll
        for (int c = 0; c < GH; ++c) {
            float s = ci[c];
#pragma unroll
            for (int d = 0; d < GH; ++d) s = fmaf(dj[d], sW1[(GH+d)*GH+c], s);
            msg[c] = fmaxf(s, 0.f);
        }
#pragma unroll
        for (int c2 = 0; c2 < GH; ++c2) {
            float s = acc[c2];
#pragma unroll
            for (int c = 0; c < GH; ++c) s = fmaf(msg[c], sW2[c*GH+c2], s);
            acc[c2] = s;
        }
    }
#pragma unroll
    for (int c = 0; c < GH; ++c) {
        acc[c] += __shfl_xor(acc[c], 1);
        acc[c] += __shfl_xor(acc[c], 2);
    }
    if (t4 == 0) {
        float* orow = hout + i * HPS;
        float v[GH];
        float sq = 0.f;
#pragma unroll
        for (int c = 0; c < GH; ++c) {
            float t = acc[c] * (1.f/16.f) + sb2[c];
            v[c] = t;
            orow[c] = t;
            sq = fmaf(t, t, sq);
        }
        orow[16] = sq;
        hT4[0*GN + i] = make_float4(v[0],  v[1],  v[2],  v[3]);
        hT4[1*GN + i] = make_float4(v[4],  v[5],  v[6],  v[7]);
        hT4[2*GN + i] = make_float4(v[8],  v[9],  v[10], v[11]);
        hT4[3*GN + i] = make_float4(v[12], v[13], v[14], v[15]);
        hTs[i] = sq;
    }
}

// ---------------------------------------------------------------------------
__global__ __launch_bounds__(256) void out_kernel(
    const float* __restrict__ hbase, const float* __restrict__ W,
    const float* __restrict__ b, void* __restrict__ out,
    const int* __restrict__ flag)
{
    int i = blockIdx.x * 256 + threadIdx.x;
    float a0 = b[0], a1 = b[1], a2 = b[2];
#pragma unroll
    for (int l = 0; l < GL; ++l) {
        const float* hp = hbase + l * GN * HPS + i * HPS;
#pragma unroll
        for (int c = 0; c < GH; ++c) {
            const float v = hp[c];
            const float* wr = W + (l * GH + c) * 3;
            a0 = fmaf(v, wr[0], a0);
            a1 = fmaf(v, wr[1], a1);
            a2 = fmaf(v, wr[2], a2);
        }
    }
    if (*flag) {
        __hip_bfloat16* o = (__hip_bfloat16*)out;
        o[i*3+0] = __float2bfloat16(a0);
        o[i*3+1] = __float2bfloat16(a1);
        o[i*3+2] = __float2bfloat16(a2);
    } else {
        float* o = (float*)out;
        o[i*3+0] = a0; o[i*3+1] = a1; o[i*3+2] = a2;
    }
}

// ---------------------------------------------------------------------------
extern "C" void kernel_launch(void* const* d_in, const int* in_sizes, int n_in,
                              void* d_out, int out_size, void* d_ws, size_t ws_size,
                              hipStream_t stream)
{
    float* wsf  = (float*)d_ws;
    int* idxb   = (int*)(wsf + OFF_IDX);
    int* flagsb = (int*)(wsf + OFF_FLAGS);
    int* dflag  = (int*)(wsf + OFF_DFLAG);
    float4* hT4 = (float4*)(wsf + OFF_HT);
    float*  hTs = wsf + OFF_HTS;

    detect_kernel<<<1, 64, 0, stream>>>((const unsigned short*)d_in[0], dflag);

    const int segoff[9] = {OFF_XF, OFF_EMBW, OFF_EMBB, OFF_W1, OFF_B1,
                           OFF_W2, OFF_B2, OFF_OW, OFF_OB};
    const int segn[9]   = {GN*3, 3*GH, GH, GL*2*GH*GH, GL*GH,
                           GL*GH*GH, GL*GH, GL*GH*3, 3};
    for (int s = 0; s < 9; ++s)
        convert_kernel<<<(segn[s] + 255)/256, 256, 0, stream>>>(
            d_in[s], wsf + segoff[s], segn[s], dflag);

    embed_kernel<<<GN/256, 256, 0, stream>>>(
        wsf + OFF_XF, wsf + OFF_EMBW, wsf + OFF_EMBB, wsf + OFF_H, hT4, hTs);

    for (int l = 0; l < GL; ++l) {
        const float* hin = wsf + OFF_H + l*GN*HPS;
        float* hout      = wsf + OFF_H + (l+1)*GN*HPS;
        knn14_kernel<<<GN/RPB, TPB, 0, stream>>>(hin, hT4, hTs, idxb, flagsb);
        rescue_kernel<<<GN/RPB, 256, 0, stream>>>(hin, flagsb, idxb);
        edgeconv_kernel<<<GN/64, 256, 0, stream>>>(hin, idxb,
            wsf + OFF_W1 + l*2*GH*GH, wsf + OFF_B1 + l*GH,
            wsf + OFF_W2 + l*GH*GH,  wsf + OFF_B2 + l*GH, hout, hT4, hTs);
    }

    out_kernel<<<GN/256, 256, 0, stream>>>(
        wsf + OFF_H + GN*HPS, wsf + OFF_OW, wsf + OFF_OB, d_out, dflag);
}